// Round 16
// baseline (236.575 us; speedup 1.0000x reference)
//
#include <hip/hip_runtime.h>
#include <hip/hip_bf16.h>
#include <stdint.h>

typedef int   intx4  __attribute__((ext_vector_type(4)));   // i8 MFMA operand / i32 acc
typedef float floatx4 __attribute__((ext_vector_type(4)));

#define BM  256
#define BN  256
#define BKB 128        // K-bytes (= i8 elems) per tile

__device__ __forceinline__ void gload_lds16(const void* g, void* l) {
    auto* gp = reinterpret_cast<const __attribute__((address_space(1))) uint32_t*>(
        reinterpret_cast<uintptr_t>(g));
    auto* lp = reinterpret_cast<__attribute__((address_space(3))) uint32_t*>(
        reinterpret_cast<uintptr_t>(l));
    __builtin_amdgcn_global_load_lds(gp, lp, 16, 0, 0);
}

// ==========================================================================
// Fused per-row quantizer. xq: row-major (LDS-staged in GEMM).
// wq: FRAGMENT-MAJOR — 1KB blocks indexed (n>>4)*(K>>6)+(k>>6); within a
// block, lane L holds row (L&15), k-chunk (L>>4): off = (n&15)*16 +
// ((k>>4)&3)*256 + (k&15). This makes each GEMM B-fragment load a single
// fully-coalesced global_load_dwordx4 (lane*16B) — fixes r11's 16-line
// scatter that made B-from-global TA-bound.
// ==========================================================================
__global__ void quant_fused(const float* __restrict__ x, const float* __restrict__ W,
                            const float* __restrict__ lA, const float* __restrict__ lB,
                            int8_t* __restrict__ xq, int8_t* __restrict__ wq,
                            float* __restrict__ sx, float* __restrict__ sw,
                            long Mrows, int N, int K, int r) {
    __shared__ float rowbuf[4096];
    __shared__ float red[4];
    const int tid = threadIdx.x;
    const long b = blockIdx.x;
    const bool isW = (b >= Mrows);
    const long row = isW ? (b - Mrows) : b;
    const int nchunk = K >> 10;                 // K/(256*4)

    float am = 0.f;
    if (!isW) {
        const float* xr = x + (size_t)row * K;
        for (int i = 0; i < nchunk; ++i) {
            float4 f = ((const float4*)xr)[i * 256 + tid];
            ((float4*)rowbuf)[i * 256 + tid] = f;
            am = fmaxf(am, fmaxf(fmaxf(fabsf(f.x), fabsf(f.y)),
                                 fmaxf(fabsf(f.z), fabsf(f.w))));
        }
    } else {
        const float* wr = W + (size_t)row * K;
        for (int i = 0; i < nchunk; ++i) {
            float4 f = ((const float4*)wr)[i * 256 + tid];
            for (int j = 0; j < r; ++j) {
                float bj = lB[row * r + j];
                float4 a = ((const float4*)(lA + (size_t)j * K))[i * 256 + tid];
                f.x += bj * a.x; f.y += bj * a.y; f.z += bj * a.z; f.w += bj * a.w;
            }
            ((float4*)rowbuf)[i * 256 + tid] = f;
            am = fmaxf(am, fmaxf(fmaxf(fabsf(f.x), fabsf(f.y)),
                                 fmaxf(fabsf(f.z), fabsf(f.w))));
        }
    }
#pragma unroll
    for (int off = 32; off; off >>= 1) am = fmaxf(am, __shfl_xor(am, off));
    if ((tid & 63) == 0) red[tid >> 6] = am;
    __syncthreads();
    am = fmaxf(fmaxf(red[0], red[1]), fmaxf(red[2], red[3]));
    const float inv = am > 0.f ? 127.0f / am : 0.f;
    if (tid == 0) {
        if (isW) sw[row] = am > 0.f ? am / 127.0f : 0.f;
        else     sx[row] = am > 0.f ? am / 127.0f : 0.f;
    }
    for (int i = 0; i < nchunk; ++i) {
        float4 f = ((const float4*)rowbuf)[i * 256 + tid];
        int q0 = min(127, max(-127, (int)rintf(f.x * inv)));
        int q1 = min(127, max(-127, (int)rintf(f.y * inv)));
        int q2 = min(127, max(-127, (int)rintf(f.z * inv)));
        int q3 = min(127, max(-127, (int)rintf(f.w * inv)));
        int packed = (q0 & 255) | ((q1 & 255) << 8) | ((q2 & 255) << 16) | (q3 << 24);
        long k = (long)(i * 256 + tid) * 4;
        if (!isW) {
            *(int*)(xq + (size_t)row * K + k) = packed;
        } else {
            size_t blk = (size_t)(row >> 4) * (K >> 6) + (k >> 6);
            size_t off = blk * 1024 + ((row & 15) << 4) + (((k >> 4) & 3) << 8) + (k & 15);
            *(int*)(wq + off) = packed;
        }
    }
}

// ==========================================================================
// i8 GEMM, full-drain sync (passed post-timing r15), B OUT OF LDS:
// B fragments load straight global->VGPR from fragment-major wq — one
// coalesced dwordx4 per fragment (8/wave/K-tile, L2-resident panel).
// LDS holds A only (2 x 32 KiB dbuf). Per K-tile: {stage A(t+1) 4 DMAs +
// load B(t+1) 8 frags | read 8 A-frags mh0, 32 MFMA | read mh1, 32 MFMA |
// vmcnt(0)+barrier}. Zero in-flight ops cross any barrier.
// A swizzle/staging byte-identical to r15 (0 conflicts).
// Regs: af 32 + bU/bV 64 + addr ~25 = ~121 VGPR + 128 AGPR <= 256 @2w/SIMD.
// ==========================================================================
__global__ __launch_bounds__(512, 2)
void gemm_i8g(const int8_t* __restrict__ A,    // [M,K] i8 row-major
              const int8_t* __restrict__ Bf,   // [N,K] i8 FRAGMENT-MAJOR
              const float* __restrict__ bias,
              const float* __restrict__ sx, const float* __restrict__ sw,
              float* __restrict__ C,           // [M,N] f32
              int M, int N, int K) {
    __shared__ __align__(16) int8_t lds[2][BM * BKB];   // A only: 64 KiB

    const int nbn = N / BN;
    const int nwg = gridDim.x;
    int bid = blockIdx.x;
    int swz = bid;
    if ((nwg & 7) == 0) swz = (bid & 7) * (nwg >> 3) + (bid >> 3);   // XCD swizzle
    const int bm = swz / nbn, bn = swz % nbn;

    const int th   = threadIdx.x;
    const int lane = th & 63;
    const int wid  = th >> 6;
    const int wm = wid >> 2;           // 0..1 -> 128-row slice
    const int wn = wid & 3;            // 0..3 -> 64-col slice
    const int lr = lane & 15;
    const int kg = lane >> 4;          // 16B granule group along K

    const int8_t* gA = A + (size_t)(bm * BM) * K;
    const int KB6 = K >> 6;
    // wave's B fragment base: blocks (bn*16 + wn*4 + n)*KB6 + kblk, lane*16
    const int8_t* gBF = Bf + ((size_t)(bn * 16 + wn * 4) * KB6) * 1024 + (size_t)lane * 16;
    const int NT = K / BKB;            // 32

    intx4 acc[8][4];
#pragma unroll
    for (int m = 0; m < 8; ++m)
#pragma unroll
        for (int n = 0; n < 4; ++n)
            acc[m][n] = (intx4){0, 0, 0, 0};

    const int trow = th >> 3;                       // 0..63 rows per G-load
    const int tgr  = (th & 7) ^ (trow & 7);         // pre-swizzled src granule

    auto stageA = [&](int dbuf, int mh, int k0) {
#pragma unroll
        for (int g = 0; g < 2; ++g) {
            int p = g * 128 + mh * 64 + trow;       // phys A row
            gload_lds16(gA + (size_t)p * K + k0 + tgr * 16,
                        &lds[dbuf][(mh * 128 + g * 64) * BKB + th * 16]);
        }
    };
    auto ldA = [&](const int8_t* base, int mh, int mp, int kk) -> intx4 {
        int l = mh * 128 + wm * 64 + mp * 16 + lr;
        int c = ((kk << 2) | kg) ^ (lr & 7);
        return *(const intx4*)(base + l * BKB + c * 16);
    };
    auto loadB = [&](intx4 (&dst)[4][2], int k0) {
        const int kb = k0 >> 6;
#pragma unroll
        for (int n = 0; n < 4; ++n)
#pragma unroll
            for (int kk = 0; kk < 2; ++kk)
                dst[n][kk] = *(const intx4*)(gBF + ((size_t)n * KB6 + kb + kk) * 1024);
    };

    intx4 bU[4][2], bV[4][2], af[4][2];

#define TILE_BODY(Abuf, bc, bnext, kn)                                          \
    {                                                                           \
        if ((kn) < K) {                                                         \
            stageA((Abuf) ^ 1, 0, (kn));                                        \
            stageA((Abuf) ^ 1, 1, (kn));                                        \
            loadB(bnext, (kn));                                                 \
        }                                                                       \
        const int8_t* Ab_ = &lds[(Abuf)][0];                                    \
        _Pragma("unroll")                                                       \
        for (int mp = 0; mp < 4; ++mp)                                          \
            _Pragma("unroll")                                                   \
            for (int kk = 0; kk < 2; ++kk)                                      \
                af[mp][kk] = ldA(Ab_, 0, mp, kk);                               \
        __builtin_amdgcn_s_setprio(1);                                          \
        _Pragma("unroll")                                                       \
        for (int mp = 0; mp < 4; ++mp)                                          \
            _Pragma("unroll")                                                   \
            for (int n = 0; n < 4; ++n)                                         \
                _Pragma("unroll")                                               \
                for (int kk = 0; kk < 2; ++kk)                                  \
                    acc[mp][n] = __builtin_amdgcn_mfma_i32_16x16x64_i8(         \
                        af[mp][kk], bc[n][kk], acc[mp][n], 0, 0, 0);            \
        __builtin_amdgcn_s_setprio(0);                                          \
        _Pragma("unroll")                                                       \
        for (int mp = 0; mp < 4; ++mp)                                          \
            _Pragma("unroll")                                                   \
            for (int kk = 0; kk < 2; ++kk)                                      \
                af[mp][kk] = ldA(Ab_, 1, mp, kk);                               \
        __builtin_amdgcn_s_setprio(1);                                          \
        _Pragma("unroll")                                                       \
        for (int mp = 0; mp < 4; ++mp)                                          \
            _Pragma("unroll")                                                   \
            for (int n = 0; n < 4; ++n)                                         \
                _Pragma("unroll")                                               \
                for (int kk = 0; kk < 2; ++kk)                                  \
                    acc[4 + mp][n] = __builtin_amdgcn_mfma_i32_16x16x64_i8(     \
                        af[mp][kk], bc[n][kk], acc[4 + mp][n], 0, 0, 0);        \
        __builtin_amdgcn_s_setprio(0);                                          \
        asm volatile("s_waitcnt vmcnt(0)" ::: "memory");                        \
        asm volatile("s_barrier" ::: "memory");                                 \
    }

    // prologue: stage A(0), load B(0) -> bU, publish (full drain)
    stageA(0, 0, 0);
    stageA(0, 1, 0);
    loadB(bU, 0);
    asm volatile("s_waitcnt vmcnt(0)" ::: "memory");
    asm volatile("s_barrier" ::: "memory");

    for (int it = 0; it < NT / 2; ++it) {
        const int u = 2 * it;
        TILE_BODY(0, bU, bV, (u + 1) * BKB);    // tile u   (A buf0), prefetch u+1
        TILE_BODY(1, bV, bU, (u + 2) * BKB);    // tile u+1 (A buf1), prefetch u+2
    }
#undef TILE_BODY

    // ---- epilogue: C/D layout col = lane&15, row = (lane>>4)*4 + q ----
    const int crow = bm * BM + wm * 128;
    const int ccol = bn * BN + wn * 64;
#pragma unroll
    for (int n = 0; n < 4; ++n) {
        int col = ccol + n * 16 + lr;
        float bv  = bias[col];
        float swc = sw[col];
#pragma unroll
        for (int m = 0; m < 8; ++m) {
            int row0 = crow + m * 16 + kg * 4;
            float4 s4 = *(const float4*)&sx[row0];     // row0 % 4 == 0
            C[(size_t)(row0 + 0) * N + col] = (float)acc[m][n][0] * (s4.x * swc) + bv;
            C[(size_t)(row0 + 1) * N + col] = (float)acc[m][n][1] * (s4.y * swc) + bv;
            C[(size_t)(row0 + 2) * N + col] = (float)acc[m][n][2] * (s4.z * swc) + bv;
            C[(size_t)(row0 + 3) * N + col] = (float)acc[m][n][3] * (s4.w * swc) + bv;
        }
    }
}

// ---------- fallback (f32, slow but correct) ----------
__global__ void xa_kernel(const float* __restrict__ x, const float* __restrict__ lA,
                          float* __restrict__ xa, long M, int K, int r) {
    long idx = (long)blockIdx.x * blockDim.x + threadIdx.x;
    long total = M * r;
    if (idx >= total) return;
    long m = idx / r; int j = (int)(idx % r);
    const float* xr = x + m * (long)K;
    const float* ar = lA + (size_t)j * K;
    float s = 0.f;
    for (int k = 0; k < K; k += 4) {
        float4 xv = *(const float4*)&xr[k];
        float4 av = *(const float4*)&ar[k];
        s += xv.x * av.x + xv.y * av.y + xv.z * av.z + xv.w * av.w;
    }
    xa[idx] = s;
}

__global__ void naive_out(const float* __restrict__ x, const float* __restrict__ W,
                          const float* __restrict__ bias, const float* __restrict__ xa,
                          const float* __restrict__ lB, float* __restrict__ out,
                          long M, int N, int K, int r) {
    long idx = (long)blockIdx.x * blockDim.x + threadIdx.x;
    long total = M * (long)N;
    if (idx >= total) return;
    long m = idx / N; int n = (int)(idx % N);
    const float* xr = x + m * (long)K;
    const float* wr = W + (size_t)n * K;
    float s = bias[n];
    for (int k = 0; k < K; k += 4) {
        float4 xv = *(const float4*)&xr[k];
        float4 wv = *(const float4*)&wr[k];
        s += xv.x * wv.x + xv.y * wv.y + xv.z * wv.z + xv.w * wv.w;
    }
    const float* xar = xa + m * r;
    const float* br  = lB + (size_t)n * r;
    for (int j = 0; j < r; ++j) s += xar[j] * br[j];
    out[idx] = s;
}

extern "C" void kernel_launch(void* const* d_in, const int* in_sizes, int n_in,
                              void* d_out, int out_size, void* d_ws, size_t ws_size,
                              hipStream_t stream) {
    const float* x    = (const float*)d_in[0];
    const float* W    = (const float*)d_in[1];
    const float* bias = (const float*)d_in[2];
    const float* lA   = (const float*)d_in[3];
    const float* lB   = (const float*)d_in[4];
    float* out = (float*)d_out;

    const int  N  = in_sizes[2];                  // d_out = 4096
    const int  Kd = in_sizes[1] / N;              // d_in  = 4096
    const int  r  = in_sizes[4] / N;              // 16
    const long M  = (long)in_sizes[0] / Kd;       // B*S   = 8192

    size_t xq_bytes = (size_t)M * Kd;             // i8
    size_t wq_bytes = (size_t)N * Kd;             // i8 fragment-major
    size_t sx_bytes = (size_t)M * sizeof(float);
    size_t sw_bytes = (size_t)N * sizeof(float);

    if (ws_size >= xq_bytes + wq_bytes + sx_bytes + sw_bytes &&
        (M % BM) == 0 && (N % BN) == 0 &&
        (Kd % BKB) == 0 && (Kd % 1024) == 0 && Kd <= 4096 &&
        (Kd / BKB) >= 2 && ((Kd / BKB) % 2) == 0) {
        int8_t* xq = (int8_t*)d_ws;
        int8_t* wq = (int8_t*)d_ws + xq_bytes;
        float*  sx = (float*)((char*)d_ws + xq_bytes + wq_bytes);
        float*  sw = sx + M;

        quant_fused<<<(int)(M + N), 256, 0, stream>>>(x, W, lA, lB, xq, wq, sx, sw,
                                                      M, N, Kd, r);

        int grid = (int)(M / BM) * (N / BN);
        gemm_i8g<<<grid, 512, 0, stream>>>(xq, wq, bias, sx, sw, out, (int)M, N, Kd);
    } else {
        // f32 fallback: xa = x @ lA^T  (M x r), then naive out
        float* xa = (float*)d_ws;   // needs M*r*4 bytes = 512 KB
        long total_xa = M * (long)r;
        int blk_xa = (int)((total_xa + 255) / 256);
        xa_kernel<<<blk_xa, 256, 0, stream>>>(x, lA, xa, M, Kd, r);
        long total_o = M * (long)N;
        int blk_o = (int)((total_o + 255) / 256);
        naive_out<<<blk_o, 256, 0, stream>>>(x, W, bias, xa, lB, out, M, N, Kd, r);
    }
}

// Round 17
// 210.153 us; speedup vs baseline: 1.1257x; 1.1257x over previous
//
#include <hip/hip_runtime.h>
#include <hip/hip_bf16.h>
#include <stdint.h>

typedef int   intx4  __attribute__((ext_vector_type(4)));   // i8 MFMA operand / i32 acc
typedef float floatx4 __attribute__((ext_vector_type(4)));

#define BM  256
#define BN  256
#define BKB 128        // K-bytes (= i8 elems) per tile

__device__ __forceinline__ void gload_lds16(const void* g, void* l) {
    auto* gp = reinterpret_cast<const __attribute__((address_space(1))) uint32_t*>(
        reinterpret_cast<uintptr_t>(g));
    auto* lp = reinterpret_cast<__attribute__((address_space(3))) uint32_t*>(
        reinterpret_cast<uintptr_t>(l));
    __builtin_amdgcn_global_load_lds(gp, lp, 16, 0, 0);
}

// ==========================================================================
// Fused per-row quantizer, REGISTER-RESIDENT (r16 change): each thread keeps
// its 16 row-values in VGPRs across the absmax reduction — no rowbuf LDS
// round-trip (was 32KB LDS traffic + 2 sync points per block). Pure-BW now.
// blocks [0,M): x rows -> xq row-major; [M,M+N): Wadj rows -> wq row-major.
// K is specialized to 4096 (nchunk=4) by the caller guard.
// ==========================================================================
__global__ void quant_fused(const float* __restrict__ x, const float* __restrict__ W,
                            const float* __restrict__ lA, const float* __restrict__ lB,
                            int8_t* __restrict__ xq, int8_t* __restrict__ wq,
                            float* __restrict__ sx, float* __restrict__ sw,
                            long Mrows, int N, int K, int r) {
    __shared__ float red[4];
    const int tid = threadIdx.x;
    const long b = blockIdx.x;
    const bool isW = (b >= Mrows);
    const long row = isW ? (b - Mrows) : b;

    float4 v[4];                       // 16 values in registers
    float am = 0.f;
    if (!isW) {
        const float* xr = x + (size_t)row * K;
#pragma unroll
        for (int i = 0; i < 4; ++i) {
            v[i] = ((const float4*)xr)[i * 256 + tid];
            am = fmaxf(am, fmaxf(fmaxf(fabsf(v[i].x), fabsf(v[i].y)),
                                 fmaxf(fabsf(v[i].z), fabsf(v[i].w))));
        }
    } else {
        const float* wr = W + (size_t)row * K;
#pragma unroll
        for (int i = 0; i < 4; ++i) {
            float4 f = ((const float4*)wr)[i * 256 + tid];
            for (int j = 0; j < r; ++j) {
                float bj = lB[row * r + j];
                float4 a = ((const float4*)(lA + (size_t)j * K))[i * 256 + tid];
                f.x += bj * a.x; f.y += bj * a.y; f.z += bj * a.z; f.w += bj * a.w;
            }
            v[i] = f;
            am = fmaxf(am, fmaxf(fmaxf(fabsf(f.x), fabsf(f.y)),
                                 fmaxf(fabsf(f.z), fabsf(f.w))));
        }
    }
#pragma unroll
    for (int off = 32; off; off >>= 1) am = fmaxf(am, __shfl_xor(am, off));
    if ((tid & 63) == 0) red[tid >> 6] = am;
    __syncthreads();
    am = fmaxf(fmaxf(red[0], red[1]), fmaxf(red[2], red[3]));
    const float inv = am > 0.f ? 127.0f / am : 0.f;
    if (tid == 0) {
        if (isW) sw[row] = am > 0.f ? am / 127.0f : 0.f;
        else     sx[row] = am > 0.f ? am / 127.0f : 0.f;
    }
    int8_t* dst = (isW ? wq : xq) + (size_t)row * K;
#pragma unroll
    for (int i = 0; i < 4; ++i) {
        int q0 = min(127, max(-127, (int)rintf(v[i].x * inv)));
        int q1 = min(127, max(-127, (int)rintf(v[i].y * inv)));
        int q2 = min(127, max(-127, (int)rintf(v[i].z * inv)));
        int q3 = min(127, max(-127, (int)rintf(v[i].w * inv)));
        int packed = (q0 & 255) | ((q1 & 255) << 8) | ((q2 & 255) << 16) | (q3 << 24);
        *(int*)(dst + ((size_t)(i * 256 + tid)) * 4) = packed;
    }
}

// ==========================================================================
// i8 GEMM — r15 VERBATIM (best measured: 159us, passed post-timing).
// Full-drain sync: one vmcnt(0)+barrier boundary per K-tile, zero in-flight
// DMA across any barrier. B in LDS (r16 proved B-from-global regresses).
// Swizzle: LDS slot s of row l holds source granule s^(l&7) (0 conflicts).
// ==========================================================================
__global__ __launch_bounds__(512, 2)
void gemm_i8d(const int8_t* __restrict__ A,   // [M,K] i8, per-row scale sx
              const int8_t* __restrict__ B,   // [N,K] i8, per-row scale sw
              const float* __restrict__ bias,
              const float* __restrict__ sx, const float* __restrict__ sw,
              float* __restrict__ C,          // [M,N] f32
              int M, int N, int K) {
    __shared__ __align__(16) int8_t lds[2][2][BM * BKB];   // 128 KiB

    const int nbn = N / BN;
    const int nwg = gridDim.x;
    int bid = blockIdx.x;
    int swz = bid;
    if ((nwg & 7) == 0) swz = (bid & 7) * (nwg >> 3) + (bid >> 3);   // XCD swizzle
    const int bm = swz / nbn, bn = swz % nbn;

    const int th   = threadIdx.x;
    const int lane = th & 63;
    const int wid  = th >> 6;
    const int wm = wid >> 2;           // 0..1 -> 128-row slice
    const int wn = wid & 3;            // 0..3 -> 64-col slice
    const int lr = lane & 15;
    const int kg = lane >> 4;          // 16B granule group along K

    const int8_t* gA = A + (size_t)(bm * BM) * K;
    const int8_t* gB = B + (size_t)(bn * BN) * K;
    const int NT = K / BKB;            // 32

    intx4 acc[8][4];
#pragma unroll
    for (int m = 0; m < 8; ++m)
#pragma unroll
        for (int n = 0; n < 4; ++n)
            acc[m][n] = (intx4){0, 0, 0, 0};

    const int trow = th >> 3;                       // 0..63 rows per G-load
    const int tgr  = (th & 7) ^ (trow & 7);         // pre-swizzled src granule

    auto stageA = [&](int dbuf, int mh, int k0) {
#pragma unroll
        for (int g = 0; g < 2; ++g) {
            int p = g * 128 + mh * 64 + trow;       // phys A row
            gload_lds16(gA + (size_t)p * K + k0 + tgr * 16,
                        &lds[dbuf][0][(mh * 128 + g * 64) * BKB + th * 16]);
        }
    };
    auto stageB = [&](int dbuf, int nh, int k0) {
#pragma unroll
        for (int g = 0; g < 2; ++g) {
            int rest = g * 64 + trow;               // 0..127
            int p = (rest >> 5) * 64 + nh * 32 + (rest & 31);   // phys B row
            gload_lds16(gB + (size_t)p * K + k0 + tgr * 16,
                        &lds[dbuf][1][(nh * 128 + g * 64) * BKB + th * 16]);
        }
    };

    auto ldA = [&](const int8_t* base, int mh, int mp, int kk) -> intx4 {
        int l = mh * 128 + wm * 64 + mp * 16 + lr;
        int c = ((kk << 2) | kg) ^ (lr & 7);
        return *(const intx4*)(base + l * BKB + c * 16);
    };
    auto ldB = [&](const int8_t* base, int nh, int np, int kk) -> intx4 {
        int l = nh * 128 + wn * 32 + np * 16 + lr;
        int c = ((kk << 2) | kg) ^ (lr & 7);
        return *(const intx4*)(base + l * BKB + c * 16);
    };

    // ---- prologue: stage tile 0, publish (full drain) ----
    stageA(0, 0, 0); stageB(0, 0, 0); stageB(0, 1, 0); stageA(0, 1, 0);
    asm volatile("s_waitcnt vmcnt(0)" ::: "memory");
    asm volatile("s_barrier" ::: "memory");

    for (int t = 0; t < NT; ++t) {
        const int8_t* Ab = &lds[t & 1][0][0];
        const int8_t* Bb = &lds[t & 1][1][0];
        const int nb = (t + 1) & 1;

        if (t + 1 < NT) {
            const int k1 = (t + 1) * BKB;
            stageA(nb, 0, k1);
            stageB(nb, 0, k1);
            stageB(nb, 1, k1);
            stageA(nb, 1, k1);
        }

        intx4 af[4][2], af2[4][2], b0[2][2], b1[2][2];
#pragma unroll
        for (int mp = 0; mp < 4; ++mp)
#pragma unroll
            for (int kk = 0; kk < 2; ++kk)
                af[mp][kk] = ldA(Ab, 0, mp, kk);
#pragma unroll
        for (int np = 0; np < 2; ++np)
#pragma unroll
            for (int kk = 0; kk < 2; ++kk)
                b0[np][kk] = ldB(Bb, 0, np, kk);
#pragma unroll
        for (int np = 0; np < 2; ++np)
#pragma unroll
            for (int kk = 0; kk < 2; ++kk)
                b1[np][kk] = ldB(Bb, 1, np, kk);
#pragma unroll
        for (int mp = 0; mp < 4; ++mp)
#pragma unroll
            for (int kk = 0; kk < 2; ++kk)
                af2[mp][kk] = ldA(Ab, 1, mp, kk);

        __builtin_amdgcn_s_setprio(1);
#pragma unroll
        for (int mp = 0; mp < 4; ++mp)
#pragma unroll
            for (int np = 0; np < 2; ++np)
#pragma unroll
                for (int kk = 0; kk < 2; ++kk)
                    acc[mp][np] = __builtin_amdgcn_mfma_i32_16x16x64_i8(
                        af[mp][kk], b0[np][kk], acc[mp][np], 0, 0, 0);
#pragma unroll
        for (int mp = 0; mp < 4; ++mp)
#pragma unroll
            for (int np = 0; np < 2; ++np)
#pragma unroll
                for (int kk = 0; kk < 2; ++kk)
                    acc[mp][2 + np] = __builtin_amdgcn_mfma_i32_16x16x64_i8(
                        af[mp][kk], b1[np][kk], acc[mp][2 + np], 0, 0, 0);
#pragma unroll
        for (int mp = 0; mp < 4; ++mp)
#pragma unroll
            for (int np = 0; np < 2; ++np)
#pragma unroll
                for (int kk = 0; kk < 2; ++kk)
                    acc[4 + mp][np] = __builtin_amdgcn_mfma_i32_16x16x64_i8(
                        af2[mp][kk], b0[np][kk], acc[4 + mp][np], 0, 0, 0);
#pragma unroll
        for (int mp = 0; mp < 4; ++mp)
#pragma unroll
            for (int np = 0; np < 2; ++np)
#pragma unroll
                for (int kk = 0; kk < 2; ++kk)
                    acc[4 + mp][2 + np] = __builtin_amdgcn_mfma_i32_16x16x64_i8(
                        af2[mp][kk], b1[np][kk], acc[4 + mp][2 + np], 0, 0, 0);
        __builtin_amdgcn_s_setprio(0);

        asm volatile("s_waitcnt vmcnt(0)" ::: "memory");
        asm volatile("s_barrier" ::: "memory");
    }

    // ---- epilogue: C/D layout col = lane&15, row = (lane>>4)*4 + q ----
    const int crow = bm * BM + wm * 128;
    const int ccol = bn * BN + wn * 64;
#pragma unroll
    for (int n = 0; n < 4; ++n) {
        int col = ccol + n * 16 + lr;
        float bv  = bias[col];
        float swc = sw[col];
#pragma unroll
        for (int m = 0; m < 8; ++m) {
            int row0 = crow + m * 16 + kg * 4;
            float4 s4 = *(const float4*)&sx[row0];     // row0 % 4 == 0
            C[(size_t)(row0 + 0) * N + col] = (float)acc[m][n][0] * (s4.x * swc) + bv;
            C[(size_t)(row0 + 1) * N + col] = (float)acc[m][n][1] * (s4.y * swc) + bv;
            C[(size_t)(row0 + 2) * N + col] = (float)acc[m][n][2] * (s4.z * swc) + bv;
            C[(size_t)(row0 + 3) * N + col] = (float)acc[m][n][3] * (s4.w * swc) + bv;
        }
    }
}

// ---------- fallback (f32, slow but correct) ----------
__global__ void xa_kernel(const float* __restrict__ x, const float* __restrict__ lA,
                          float* __restrict__ xa, long M, int K, int r) {
    long idx = (long)blockIdx.x * blockDim.x + threadIdx.x;
    long total = M * r;
    if (idx >= total) return;
    long m = idx / r; int j = (int)(idx % r);
    const float* xr = x + m * (long)K;
    const float* ar = lA + (size_t)j * K;
    float s = 0.f;
    for (int k = 0; k < K; k += 4) {
        float4 xv = *(const float4*)&xr[k];
        float4 av = *(const float4*)&ar[k];
        s += xv.x * av.x + xv.y * av.y + xv.z * av.z + xv.w * av.w;
    }
    xa[idx] = s;
}

__global__ void naive_out(const float* __restrict__ x, const float* __restrict__ W,
                          const float* __restrict__ bias, const float* __restrict__ xa,
                          const float* __restrict__ lB, float* __restrict__ out,
                          long M, int N, int K, int r) {
    long idx = (long)blockIdx.x * blockDim.x + threadIdx.x;
    long total = M * (long)N;
    if (idx >= total) return;
    long m = idx / N; int n = (int)(idx % N);
    const float* xr = x + m * (long)K;
    const float* wr = W + (size_t)n * K;
    float s = bias[n];
    for (int k = 0; k < K; k += 4) {
        float4 xv = *(const float4*)&xr[k];
        float4 wv = *(const float4*)&wr[k];
        s += xv.x * wv.x + xv.y * wv.y + xv.z * wv.z + xv.w * wv.w;
    }
    const float* xar = xa + m * r;
    const float* br  = lB + (size_t)n * r;
    for (int j = 0; j < r; ++j) s += xar[j] * br[j];
    out[idx] = s;
}

extern "C" void kernel_launch(void* const* d_in, const int* in_sizes, int n_in,
                              void* d_out, int out_size, void* d_ws, size_t ws_size,
                              hipStream_t stream) {
    const float* x    = (const float*)d_in[0];
    const float* W    = (const float*)d_in[1];
    const float* bias = (const float*)d_in[2];
    const float* lA   = (const float*)d_in[3];
    const float* lB   = (const float*)d_in[4];
    float* out = (float*)d_out;

    const int  N  = in_sizes[2];                  // d_out = 4096
    const int  Kd = in_sizes[1] / N;              // d_in  = 4096
    const int  r  = in_sizes[4] / N;              // 16
    const long M  = (long)in_sizes[0] / Kd;       // B*S   = 8192

    size_t xq_bytes = (size_t)M * Kd;             // i8
    size_t wq_bytes = (size_t)N * Kd;             // i8
    size_t sx_bytes = (size_t)M * sizeof(float);
    size_t sw_bytes = (size_t)N * sizeof(float);

    if (ws_size >= xq_bytes + wq_bytes + sx_bytes + sw_bytes &&
        (M % BM) == 0 && (N % BN) == 0 &&
        Kd == 4096 && (Kd / BKB) >= 2) {
        int8_t* xq = (int8_t*)d_ws;
        int8_t* wq = (int8_t*)d_ws + xq_bytes;
        float*  sx = (float*)((char*)d_ws + xq_bytes + wq_bytes);
        float*  sw = sx + M;

        quant_fused<<<(int)(M + N), 256, 0, stream>>>(x, W, lA, lB, xq, wq, sx, sw,
                                                      M, N, Kd, r);

        int grid = (int)(M / BM) * (N / BN);
        gemm_i8d<<<grid, 512, 0, stream>>>(xq, wq, bias, sx, sw, out, (int)M, N, Kd);
    } else {
        // f32 fallback: xa = x @ lA^T  (M x r), then naive out
        float* xa = (float*)d_ws;   // needs M*r*4 bytes = 512 KB
        long total_xa = M * (long)r;
        int blk_xa = (int)((total_xa + 255) / 256);
        xa_kernel<<<blk_xa, 256, 0, stream>>>(x, lA, xa, M, Kd, r);
        long total_o = M * (long)N;
        int blk_o = (int)((total_o + 255) / 256);
        naive_out<<<blk_o, 256, 0, stream>>>(x, W, bias, xa, lB, out, M, N, Kd, r);
    }
}

// Round 18
// 195.967 us; speedup vs baseline: 1.2072x; 1.0724x over previous
//
#include <hip/hip_runtime.h>
#include <hip/hip_bf16.h>
#include <stdint.h>

typedef int   intx4  __attribute__((ext_vector_type(4)));   // i8 MFMA operand / i32 acc
typedef float floatx4 __attribute__((ext_vector_type(4)));

#define BM  256
#define BN  256
#define BKB 128        // K-bytes (= i8 elems) per tile

__device__ __forceinline__ void gload_lds16(const void* g, void* l) {
    auto* gp = reinterpret_cast<const __attribute__((address_space(1))) uint32_t*>(
        reinterpret_cast<uintptr_t>(g));
    auto* lp = reinterpret_cast<__attribute__((address_space(3))) uint32_t*>(
        reinterpret_cast<uintptr_t>(l));
    __builtin_amdgcn_global_load_lds(gp, lp, 16, 0, 0);
}

// ==========================================================================
// Fused per-row quantizer, register-resident (r17) + r18 change:
// W-part processes FOUR rows per block, so each lA chunk is read once and
// applied to 4 register-resident rows -> lA L2 traffic 1.07GB -> 268MB
// (was ~31us of aggregate L2 bandwidth). Per-row math bit-identical.
// blocks [0,M): x rows -> xq; [M, M+N/4): 4 W-rows each -> wq.
// K specialized to 4096 (chunks of 256 thr x float4 x 4).
// ==========================================================================
__global__ void quant_fused(const float* __restrict__ x, const float* __restrict__ W,
                            const float* __restrict__ lA, const float* __restrict__ lB,
                            int8_t* __restrict__ xq, int8_t* __restrict__ wq,
                            float* __restrict__ sx, float* __restrict__ sw,
                            long Mrows, int N, int K, int r) {
    __shared__ float red[4][4];        // [row][wave]
    const int tid = threadIdx.x;
    const int wv  = tid >> 6;
    const long b = blockIdx.x;

    if (b < Mrows) {
        // ---- x-part: one row, register-resident (r17 verbatim) ----
        const long row = b;
        const float* xr = x + (size_t)row * K;
        float4 v[4];
        float am = 0.f;
#pragma unroll
        for (int i = 0; i < 4; ++i) {
            v[i] = ((const float4*)xr)[i * 256 + tid];
            am = fmaxf(am, fmaxf(fmaxf(fabsf(v[i].x), fabsf(v[i].y)),
                                 fmaxf(fabsf(v[i].z), fabsf(v[i].w))));
        }
#pragma unroll
        for (int off = 32; off; off >>= 1) am = fmaxf(am, __shfl_xor(am, off));
        if ((tid & 63) == 0) red[0][wv] = am;
        __syncthreads();
        am = fmaxf(fmaxf(red[0][0], red[0][1]), fmaxf(red[0][2], red[0][3]));
        const float inv = am > 0.f ? 127.0f / am : 0.f;
        if (tid == 0) sx[row] = am > 0.f ? am / 127.0f : 0.f;
        int8_t* dst = xq + (size_t)row * K;
#pragma unroll
        for (int i = 0; i < 4; ++i) {
            int q0 = min(127, max(-127, (int)rintf(v[i].x * inv)));
            int q1 = min(127, max(-127, (int)rintf(v[i].y * inv)));
            int q2 = min(127, max(-127, (int)rintf(v[i].z * inv)));
            int q3 = min(127, max(-127, (int)rintf(v[i].w * inv)));
            int packed = (q0 & 255) | ((q1 & 255) << 8) | ((q2 & 255) << 16) | (q3 << 24);
            *(int*)(dst + ((size_t)(i * 256 + tid)) * 4) = packed;
        }
    } else {
        // ---- W-part: FOUR rows per block, lA chunk loaded once per 4 rows ----
        const long w0 = (b - Mrows) * 4;
        float4 v[4][4];                // [row][chunk]
#pragma unroll
        for (int rr = 0; rr < 4; ++rr) {
            const float* wr = W + (size_t)(w0 + rr) * K;
#pragma unroll
            for (int i = 0; i < 4; ++i)
                v[rr][i] = ((const float4*)wr)[i * 256 + tid];
        }
        for (int j = 0; j < r; ++j) {
            const float* ar = lA + (size_t)j * K;
            float b0 = lB[(w0 + 0) * r + j];
            float b1 = lB[(w0 + 1) * r + j];
            float b2 = lB[(w0 + 2) * r + j];
            float b3 = lB[(w0 + 3) * r + j];
#pragma unroll
            for (int i = 0; i < 4; ++i) {
                float4 a = ((const float4*)ar)[i * 256 + tid];
                v[0][i].x += b0 * a.x; v[0][i].y += b0 * a.y; v[0][i].z += b0 * a.z; v[0][i].w += b0 * a.w;
                v[1][i].x += b1 * a.x; v[1][i].y += b1 * a.y; v[1][i].z += b1 * a.z; v[1][i].w += b1 * a.w;
                v[2][i].x += b2 * a.x; v[2][i].y += b2 * a.y; v[2][i].z += b2 * a.z; v[2][i].w += b2 * a.w;
                v[3][i].x += b3 * a.x; v[3][i].y += b3 * a.y; v[3][i].z += b3 * a.z; v[3][i].w += b3 * a.w;
            }
        }
#pragma unroll
        for (int rr = 0; rr < 4; ++rr) {
            float a = 0.f;
#pragma unroll
            for (int i = 0; i < 4; ++i)
                a = fmaxf(a, fmaxf(fmaxf(fabsf(v[rr][i].x), fabsf(v[rr][i].y)),
                                   fmaxf(fabsf(v[rr][i].z), fabsf(v[rr][i].w))));
#pragma unroll
            for (int off = 32; off; off >>= 1) a = fmaxf(a, __shfl_xor(a, off));
            if ((tid & 63) == 0) red[rr][wv] = a;
        }
        __syncthreads();
#pragma unroll
        for (int rr = 0; rr < 4; ++rr) {
            float a = fmaxf(fmaxf(red[rr][0], red[rr][1]), fmaxf(red[rr][2], red[rr][3]));
            const float inv = a > 0.f ? 127.0f / a : 0.f;
            if (tid == 0) sw[w0 + rr] = a > 0.f ? a / 127.0f : 0.f;
            int8_t* dst = wq + (size_t)(w0 + rr) * K;
#pragma unroll
            for (int i = 0; i < 4; ++i) {
                int q0 = min(127, max(-127, (int)rintf(v[rr][i].x * inv)));
                int q1 = min(127, max(-127, (int)rintf(v[rr][i].y * inv)));
                int q2 = min(127, max(-127, (int)rintf(v[rr][i].z * inv)));
                int q3 = min(127, max(-127, (int)rintf(v[rr][i].w * inv)));
                int packed = (q0 & 255) | ((q1 & 255) << 8) | ((q2 & 255) << 16) | (q3 << 24);
                *(int*)(dst + ((size_t)(i * 256 + tid)) * 4) = packed;
            }
        }
    }
}

// ==========================================================================
// i8 GEMM — r15/r17 VERBATIM (157-159us, post-timing-stable twice).
// Full-drain sync: one vmcnt(0)+barrier boundary per K-tile, zero in-flight
// DMA across any barrier. B in LDS (B-from-global regressed twice).
// Swizzle: LDS slot s of row l holds source granule s^(l&7) (0 conflicts).
// ==========================================================================
__global__ __launch_bounds__(512, 2)
void gemm_i8d(const int8_t* __restrict__ A,   // [M,K] i8, per-row scale sx
              const int8_t* __restrict__ B,   // [N,K] i8, per-row scale sw
              const float* __restrict__ bias,
              const float* __restrict__ sx, const float* __restrict__ sw,
              float* __restrict__ C,          // [M,N] f32
              int M, int N, int K) {
    __shared__ __align__(16) int8_t lds[2][2][BM * BKB];   // 128 KiB

    const int nbn = N / BN;
    const int nwg = gridDim.x;
    int bid = blockIdx.x;
    int swz = bid;
    if ((nwg & 7) == 0) swz = (bid & 7) * (nwg >> 3) + (bid >> 3);   // XCD swizzle
    const int bm = swz / nbn, bn = swz % nbn;

    const int th   = threadIdx.x;
    const int lane = th & 63;
    const int wid  = th >> 6;
    const int wm = wid >> 2;           // 0..1 -> 128-row slice
    const int wn = wid & 3;            // 0..3 -> 64-col slice
    const int lr = lane & 15;
    const int kg = lane >> 4;          // 16B granule group along K

    const int8_t* gA = A + (size_t)(bm * BM) * K;
    const int8_t* gB = B + (size_t)(bn * BN) * K;
    const int NT = K / BKB;            // 32

    intx4 acc[8][4];
#pragma unroll
    for (int m = 0; m < 8; ++m)
#pragma unroll
        for (int n = 0; n < 4; ++n)
            acc[m][n] = (intx4){0, 0, 0, 0};

    const int trow = th >> 3;                       // 0..63 rows per G-load
    const int tgr  = (th & 7) ^ (trow & 7);         // pre-swizzled src granule

    auto stageA = [&](int dbuf, int mh, int k0) {
#pragma unroll
        for (int g = 0; g < 2; ++g) {
            int p = g * 128 + mh * 64 + trow;       // phys A row
            gload_lds16(gA + (size_t)p * K + k0 + tgr * 16,
                        &lds[dbuf][0][(mh * 128 + g * 64) * BKB + th * 16]);
        }
    };
    auto stageB = [&](int dbuf, int nh, int k0) {
#pragma unroll
        for (int g = 0; g < 2; ++g) {
            int rest = g * 64 + trow;               // 0..127
            int p = (rest >> 5) * 64 + nh * 32 + (rest & 31);   // phys B row
            gload_lds16(gB + (size_t)p * K + k0 + tgr * 16,
                        &lds[dbuf][1][(nh * 128 + g * 64) * BKB + th * 16]);
        }
    };

    auto ldA = [&](const int8_t* base, int mh, int mp, int kk) -> intx4 {
        int l = mh * 128 + wm * 64 + mp * 16 + lr;
        int c = ((kk << 2) | kg) ^ (lr & 7);
        return *(const intx4*)(base + l * BKB + c * 16);
    };
    auto ldB = [&](const int8_t* base, int nh, int np, int kk) -> intx4 {
        int l = nh * 128 + wn * 32 + np * 16 + lr;
        int c = ((kk << 2) | kg) ^ (lr & 7);
        return *(const intx4*)(base + l * BKB + c * 16);
    };

    // ---- prologue: stage tile 0, publish (full drain) ----
    stageA(0, 0, 0); stageB(0, 0, 0); stageB(0, 1, 0); stageA(0, 1, 0);
    asm volatile("s_waitcnt vmcnt(0)" ::: "memory");
    asm volatile("s_barrier" ::: "memory");

    for (int t = 0; t < NT; ++t) {
        const int8_t* Ab = &lds[t & 1][0][0];
        const int8_t* Bb = &lds[t & 1][1][0];
        const int nb = (t + 1) & 1;

        if (t + 1 < NT) {
            const int k1 = (t + 1) * BKB;
            stageA(nb, 0, k1);
            stageB(nb, 0, k1);
            stageB(nb, 1, k1);
            stageA(nb, 1, k1);
        }

        intx4 af[4][2], af2[4][2], b0[2][2], b1[2][2];
#pragma unroll
        for (int mp = 0; mp < 4; ++mp)
#pragma unroll
            for (int kk = 0; kk < 2; ++kk)
                af[mp][kk] = ldA(Ab, 0, mp, kk);
#pragma unroll
        for (int np = 0; np < 2; ++np)
#pragma unroll
            for (int kk = 0; kk < 2; ++kk)
                b0[np][kk] = ldB(Bb, 0, np, kk);
#pragma unroll
        for (int np = 0; np < 2; ++np)
#pragma unroll
            for (int kk = 0; kk < 2; ++kk)
                b1[np][kk] = ldB(Bb, 1, np, kk);
#pragma unroll
        for (int mp = 0; mp < 4; ++mp)
#pragma unroll
            for (int kk = 0; kk < 2; ++kk)
                af2[mp][kk] = ldA(Ab, 1, mp, kk);

        __builtin_amdgcn_s_setprio(1);
#pragma unroll
        for (int mp = 0; mp < 4; ++mp)
#pragma unroll
            for (int np = 0; np < 2; ++np)
#pragma unroll
                for (int kk = 0; kk < 2; ++kk)
                    acc[mp][np] = __builtin_amdgcn_mfma_i32_16x16x64_i8(
                        af[mp][kk], b0[np][kk], acc[mp][np], 0, 0, 0);
#pragma unroll
        for (int mp = 0; mp < 4; ++mp)
#pragma unroll
            for (int np = 0; np < 2; ++np)
#pragma unroll
                for (int kk = 0; kk < 2; ++kk)
                    acc[mp][2 + np] = __builtin_amdgcn_mfma_i32_16x16x64_i8(
                        af[mp][kk], b1[np][kk], acc[mp][2 + np], 0, 0, 0);
#pragma unroll
        for (int mp = 0; mp < 4; ++mp)
#pragma unroll
            for (int np = 0; np < 2; ++np)
#pragma unroll
                for (int kk = 0; kk < 2; ++kk)
                    acc[4 + mp][np] = __builtin_amdgcn_mfma_i32_16x16x64_i8(
                        af2[mp][kk], b0[np][kk], acc[4 + mp][np], 0, 0, 0);
#pragma unroll
        for (int mp = 0; mp < 4; ++mp)
#pragma unroll
            for (int np = 0; np < 2; ++np)
#pragma unroll
                for (int kk = 0; kk < 2; ++kk)
                    acc[4 + mp][2 + np] = __builtin_amdgcn_mfma_i32_16x16x64_i8(
                        af2[mp][kk], b1[np][kk], acc[4 + mp][2 + np], 0, 0, 0);
        __builtin_amdgcn_s_setprio(0);

        asm volatile("s_waitcnt vmcnt(0)" ::: "memory");
        asm volatile("s_barrier" ::: "memory");
    }

    // ---- epilogue: C/D layout col = lane&15, row = (lane>>4)*4 + q ----
    const int crow = bm * BM + wm * 128;
    const int ccol = bn * BN + wn * 64;
#pragma unroll
    for (int n = 0; n < 4; ++n) {
        int col = ccol + n * 16 + lr;
        float bv  = bias[col];
        float swc = sw[col];
#pragma unroll
        for (int m = 0; m < 8; ++m) {
            int row0 = crow + m * 16 + kg * 4;
            float4 s4 = *(const float4*)&sx[row0];     // row0 % 4 == 0
            C[(size_t)(row0 + 0) * N + col] = (float)acc[m][n][0] * (s4.x * swc) + bv;
            C[(size_t)(row0 + 1) * N + col] = (float)acc[m][n][1] * (s4.y * swc) + bv;
            C[(size_t)(row0 + 2) * N + col] = (float)acc[m][n][2] * (s4.z * swc) + bv;
            C[(size_t)(row0 + 3) * N + col] = (float)acc[m][n][3] * (s4.w * swc) + bv;
        }
    }
}

// ---------- fallback (f32, slow but correct) ----------
__global__ void xa_kernel(const float* __restrict__ x, const float* __restrict__ lA,
                          float* __restrict__ xa, long M, int K, int r) {
    long idx = (long)blockIdx.x * blockDim.x + threadIdx.x;
    long total = M * r;
    if (idx >= total) return;
    long m = idx / r; int j = (int)(idx % r);
    const float* xr = x + m * (long)K;
    const float* ar = lA + (size_t)j * K;
    float s = 0.f;
    for (int k = 0; k < K; k += 4) {
        float4 xv = *(const float4*)&xr[k];
        float4 av = *(const float4*)&ar[k];
        s += xv.x * av.x + xv.y * av.y + xv.z * av.z + xv.w * av.w;
    }
    xa[idx] = s;
}

__global__ void naive_out(const float* __restrict__ x, const float* __restrict__ W,
                          const float* __restrict__ bias, const float* __restrict__ xa,
                          const float* __restrict__ lB, float* __restrict__ out,
                          long M, int N, int K, int r) {
    long idx = (long)blockIdx.x * blockDim.x + threadIdx.x;
    long total = M * (long)N;
    if (idx >= total) return;
    long m = idx / N; int n = (int)(idx % N);
    const float* xr = x + m * (long)K;
    const float* wr = W + (size_t)n * K;
    float s = bias[n];
    for (int k = 0; k < K; k += 4) {
        float4 xv = *(const float4*)&xr[k];
        float4 wv = *(const float4*)&wr[k];
        s += xv.x * wv.x + xv.y * wv.y + xv.z * wv.z + xv.w * wv.w;
    }
    const float* xar = xa + m * r;
    const float* br  = lB + (size_t)n * r;
    for (int j = 0; j < r; ++j) s += xar[j] * br[j];
    out[idx] = s;
}

extern "C" void kernel_launch(void* const* d_in, const int* in_sizes, int n_in,
                              void* d_out, int out_size, void* d_ws, size_t ws_size,
                              hipStream_t stream) {
    const float* x    = (const float*)d_in[0];
    const float* W    = (const float*)d_in[1];
    const float* bias = (const float*)d_in[2];
    const float* lA   = (const float*)d_in[3];
    const float* lB   = (const float*)d_in[4];
    float* out = (float*)d_out;

    const int  N  = in_sizes[2];                  // d_out = 4096
    const int  Kd = in_sizes[1] / N;              // d_in  = 4096
    const int  r  = in_sizes[4] / N;              // 16
    const long M  = (long)in_sizes[0] / Kd;       // B*S   = 8192

    size_t xq_bytes = (size_t)M * Kd;             // i8
    size_t wq_bytes = (size_t)N * Kd;             // i8
    size_t sx_bytes = (size_t)M * sizeof(float);
    size_t sw_bytes = (size_t)N * sizeof(float);

    if (ws_size >= xq_bytes + wq_bytes + sx_bytes + sw_bytes &&
        (M % BM) == 0 && (N % BN) == 0 && (N % 4) == 0 &&
        Kd == 4096 && (Kd / BKB) >= 2) {
        int8_t* xq = (int8_t*)d_ws;
        int8_t* wq = (int8_t*)d_ws + xq_bytes;
        float*  sx = (float*)((char*)d_ws + xq_bytes + wq_bytes);
        float*  sw = sx + M;

        quant_fused<<<(int)(M + N / 4), 256, 0, stream>>>(x, W, lA, lB, xq, wq, sx, sw,
                                                          M, N, Kd, r);

        int grid = (int)(M / BM) * (N / BN);
        gemm_i8d<<<grid, 512, 0, stream>>>(xq, wq, bias, sx, sw, out, (int)M, N, Kd);
    } else {
        // f32 fallback: xa = x @ lA^T  (M x r), then naive out
        float* xa = (float*)d_ws;   // needs M*r*4 bytes = 512 KB
        long total_xa = M * (long)r;
        int blk_xa = (int)((total_xa + 255) / 256);
        xa_kernel<<<blk_xa, 256, 0, stream>>>(x, lA, xa, M, Kd, r);
        long total_o = M * (long)N;
        int blk_o = (int)((total_o + 255) / 256);
        naive_out<<<blk_o, 256, 0, stream>>>(x, W, bias, xa, lB, out, M, N, Kd, r);
    }
}